// Round 17
// baseline (38.266 us; speedup 1.0000x reference)
//
#include <hip/hip_runtime.h>
#include <math.h>

#define ND 64
#define NPTS (4 * ND * ND * ND)   // 1,048,576
#define SXG (ND * ND * 3)         // 12288
#define SYG (ND * 3)              // 192
#define XSEG 8                    // x-steps marched per wave

struct f3 { float v[3]; };

__device__ __forceinline__ f3 comb2(float a, const f3& X, float s, const f3& Y) {
    f3 r;
#pragma unroll
    for (int c = 0; c < 3; c++) r.v[c] = a * X.v[c] + s * Y.v[c];
    return r;
}
__device__ __forceinline__ f3 comb3(float a, const f3& X, float s, const f3& Y, float u, const f3& Z) {
    f3 r;
#pragma unroll
    for (int c = 0; c < 3; c++) r.v[c] = a * X.v[c] + s * Y.v[c] + u * Z.v[c];
    return r;
}

// physics residual norm; H symmetric [c][6]: 0=xx 1=yy 2=zz 3=xy 4=xz 5=yz
// (verified r3-r16, absmax 0.0). Tail factored (r16-verified identity):
//   v = MU*divF + kJ*trg[m] + c2*s1,  kJ=(halfL-MU)*invJ, c2=LMBD-kJ*invJ
__device__ __forceinline__ float phys_norm(const float F[3][3], const float H[3][6]) {
    constexpr int SYM[3][3] = {{0, 3, 4}, {3, 1, 5}, {4, 5, 2}};

    float cof[3][3];
#pragma unroll
    for (int i = 0; i < 3; i++) {
        const int i1 = (i + 1) % 3, i2 = (i + 2) % 3;
#pragma unroll
        for (int j = 0; j < 3; j++) {
            const int j1 = (j + 1) % 3, j2 = (j + 2) % 3;
            cof[i][j] = F[i1][j1] * F[i2][j2] - F[i1][j2] * F[i2][j1];
        }
    }

    float gc0[3][3], trg[3];
#pragma unroll
    for (int m = 0; m < 3; m++) {
        const int m1 = (m + 1) % 3, m2 = (m + 2) % 3;
        trg[m] = 0.0f;
#pragma unroll
        for (int i = 0; i < 3; i++) {
            const int i1 = (i + 1) % 3, i2 = (i + 2) % 3;
#pragma unroll
            for (int j = 0; j < 3; j++) {
                if (i == 0 || i == j) {
                    const float g = F[m2][i2] * H[m1][SYM[i1][j]] + F[m1][i1] * H[m2][SYM[i2][j]]
                                  - F[m2][i1] * H[m1][SYM[i2][j]] - F[m1][i2] * H[m2][SYM[i1][j]];
                    if (i == 0) gc0[m][j] = g;
                    if (i == j) trg[m] += g;
                }
            }
        }
    }

    const float J = F[0][0] * cof[0][0] + F[1][0] * cof[1][0] + F[2][0] * cof[2][0] + 1e-8f;
    const float invJ = 1.0f / J;

    float gJ[3];
#pragma unroll
    for (int j = 0; j < 3; j++) {
        gJ[j] = cof[0][0] * H[0][SYM[0][j]] + cof[1][0] * H[1][SYM[0][j]] + cof[2][0] * H[2][SYM[0][j]]
              + gc0[0][j] * F[0][0] + gc0[1][j] * F[1][0] + gc0[2][j] * F[2][0];
    }

    const float MU = 1000.0f, LMBD = 5000.0f;
    const float halfL = 0.5f * LMBD * (J * J - 1.0f);
    const float kJ = (halfL - MU) * invJ;
    const float c2 = LMBD - kJ * invJ;
    float r[3];
#pragma unroll
    for (int m = 0; m < 3; m++) {
        const float s1 = gJ[0] * cof[m][0] + gJ[1] * cof[m][1] + gJ[2] * cof[m][2];
        const float divF = H[m][0] + H[m][1] + H[m][2];
        float v = MU * divF + kJ * trg[m] + c2 * s1;
        r[m] = (v != v) ? 0.0f : v;   // NaN -> 0
    }
    return sqrtf(r[0] * r[0] + r[1] * r[1] + r[2] * r[2]);
}

// Per-lane z-stencil coefficients (lane == z), verified r14 (absmax 0.0):
//   G2  = a1*d1r + a2*u1r + a3*vC
//   Hzz = b1*d1r + b2*u1r + b3*d2r + b4*u2r + b5*vC
//   Hcz = e1*Ds  + e2*Us  + e3*S     (S = difference field, D/U = shfl z+-1)
struct ZC { float a1, a2, a3, b1, b2, b3, b4, b5, e1, e2, e3; };

__device__ __forceinline__ void comp_row(
        float vC, float Sx, float Sy, float sx2, float sy2, float dga,
        int ip1, int im1, int ip2, int im2, const ZC& q,
        float G[3], float Hr[6]) {
    const float d1r = __shfl(vC, ip1, 64), u1r = __shfl(vC, im1, 64);
    const float d2r = __shfl(vC, ip2, 64), u2r = __shfl(vC, im2, 64);
    const float Dx = __shfl(Sx, ip1, 64), Ux = __shfl(Sx, im1, 64);
    const float Dy = __shfl(Sy, ip1, 64), Uy = __shfl(Sy, im1, 64);

    G[0] = 0.5f * Sx;
    G[1] = 0.5f * Sy;
    G[2] = q.a1 * d1r + q.a2 * u1r + q.a3 * vC;
    Hr[0] = 0.25f * sx2 - 0.5f * vC;
    Hr[1] = 0.25f * sy2 - 0.5f * vC;
    Hr[2] = q.b1 * d1r + q.b2 * u1r + q.b3 * d2r + q.b4 * u2r + q.b5 * vC;
    Hr[3] = 0.25f * dga;
    Hr[4] = q.e1 * Dx + q.e2 * Ux + q.e3 * Sx;
    Hr[5] = q.e1 * Dy + q.e2 * Uy + q.e3 * Sy;
}

__global__ __launch_bounds__(512) void phys_loss_kernel(
        const float* __restrict__ pred,
        const float* __restrict__ targ,
        float* __restrict__ out) {
    const int t = threadIdx.x;
    const int lane = t & 63;
    const int wid = t >> 6;
    const int w = blockIdx.x * 8 + wid;     // 2048 waves
    const int y = w & 63;
    const int xseg = (w >> 6) & 7;
    const int b = w >> 9;
    const int z = lane;
    const int X0 = xseg * XSEG;

    const float* __restrict__ pb = pred + (size_t)b * (ND * SXG);
    const float* __restrict__ tb = targ + (size_t)b * (ND * SXG);
    const int yc1p = min(y + 1, 63), yc1m = max(y - 1, 0);
    const int yc2p = min(y + 2, 63), yc2m = max(y - 2, 0);

#define LDP(gx, gy) (*(const f3*)(pb + (size_t)((gx) * SXG + (gy) * SYG + z * 3)))

    auto fixy1 = [&](const f3& ypl, const f3& yml, const f3& cg, f3& ypc, f3& ymc) {
        if (y == 0)       { ypc = ypl; ymc = comb2(2.f, cg, -1.f, ypl); }
        else if (y == 63) { ymc = yml; ypc = comb2(2.f, cg, -1.f, yml); }
        else              { ypc = ypl; ymc = yml; }
    };
    auto fixy2 = [&](const f3& yp2l, const f3& ym2l, const f3& c0,
                     const f3& yp1, const f3& ym1, f3& o_p, f3& o_m) {
        if (y == 0)       { o_p = yp2l; o_m = comb3(4.f, c0, -4.f, yp1, 1.f, yp2l); }
        else if (y == 1)  { o_p = yp2l; o_m = comb2(2.f, ym1, -1.f, c0); }
        else if (y == 62) { o_m = ym2l; o_p = comb2(2.f, yp1, -1.f, c0); }
        else if (y == 63) { o_m = ym2l; o_p = comb3(4.f, c0, -4.f, ym1, 1.f, ym2l); }
        else              { o_p = yp2l; o_m = ym2l; }
    };

    // ---- prologue: windows for x0 = X0 ----
    f3 cc[5], cyp[3], cym[3], yp2, ym2;
    if (X0 == 0) {
        cc[2] = LDP(0, y); cc[3] = LDP(1, y); cc[4] = LDP(2, y);
        cc[1] = comb2(2.f, cc[2], -1.f, cc[3]);
        cc[0] = comb3(4.f, cc[2], -4.f, cc[3], 1.f, cc[4]);
        { f3 a = LDP(0, yc1p), bq = LDP(0, yc1m); fixy1(a, bq, cc[2], cyp[1], cym[1]); }
        { f3 a = LDP(1, yc1p), bq = LDP(1, yc1m); fixy1(a, bq, cc[3], cyp[2], cym[2]); }
        cyp[0] = comb2(2.f, cyp[1], -1.f, cyp[2]);
        cym[0] = comb2(2.f, cym[1], -1.f, cym[2]);
    } else {
#pragma unroll
        for (int k = 0; k < 5; k++) cc[k] = LDP(X0 - 2 + k, y);
#pragma unroll
        for (int k = 0; k < 3; k++) {
            f3 a = LDP(X0 - 1 + k, yc1p), bq = LDP(X0 - 1 + k, yc1m);
            fixy1(a, bq, cc[k + 1], cyp[k], cym[k]);
        }
    }
    { f3 a = LDP(X0, yc2p), bq = LDP(X0, yc2m);
      fixy2(a, bq, cc[2], cyp[1], cym[1], yp2, ym2); }

    // ---- per-lane z-stencil coefficients (once per wave) ----
    ZC q = {0.5f, -0.5f, 0.f,  0.f, 0.f, 0.25f, 0.25f, -0.5f,  0.25f, -0.25f, 0.f};
    if (z == 0)  { q = {1.f, 0.f, -1.f,  -1.f, 0.f, 0.5f, 0.f, 0.5f,   0.5f, 0.f, -0.5f}; }
    if (z == 1)  { q.b1 = 0.f; q.b2 = 0.5f; q.b3 = 0.25f; q.b4 = 0.f; q.b5 = -0.75f; }
    if (z == 62) { q.b1 = 0.5f; q.b2 = 0.f; q.b3 = 0.f; q.b4 = 0.25f; q.b5 = -0.75f; }
    if (z == 63) { q = {0.f, -1.f, 1.f,  0.f, -1.f, 0.f, 0.5f, 0.5f,  0.f, -0.5f, 0.5f}; }

    const int ip1 = (lane + 1) & 63, im1 = (lane + 63) & 63;
    const int ip2 = (lane + 2) & 63, im2 = (lane + 62) & 63;

    float accn = 0.f, accs = 0.f;

#pragma unroll 2
    for (int i = 0; i < XSEG; i++) {
        const int x0 = X0 + i;

        // ---- prefetch raw (clamped) columns for next step ----
        f3 cin, ypin, ymin, yp2in, ym2in;
        if (i < XSEG - 1) {
            const int gxc = min(x0 + 3, 63);
            const int gx1 = min(x0 + 2, 63);
            cin  = LDP(gxc, y);
            ypin = LDP(gx1, yc1p);  ymin = LDP(gx1, yc1m);
            yp2in = LDP(x0 + 1, yc2p);  ym2in = LDP(x0 + 1, yc2m);
        }
        const f3 T = *(const f3*)(tb + (size_t)(x0 * SXG + y * SYG + z * 3));

        // ---- compute current step from windows ----
        float F[3][3], H[3][6], G[3];
#pragma unroll
        for (int c = 0; c < 3; c++) {
            const float Sx  = cc[3].v[c] - cc[1].v[c];
            const float Sy  = cyp[1].v[c] - cym[1].v[c];
            const float sx2 = cc[4].v[c] + cc[0].v[c];
            const float sy2 = yp2.v[c] + ym2.v[c];
            const float dga = (cyp[2].v[c] - cyp[0].v[c]) - (cym[2].v[c] - cym[0].v[c]);
            comp_row(cc[2].v[c], Sx, Sy, sx2, sy2, dga,
                     ip1, im1, ip2, im2, q, G, H[c]);
            F[c][0] = G[0] + ((c == 0) ? 1.f : 0.f);
            F[c][1] = G[1] + ((c == 1) ? 1.f : 0.f);
            F[c][2] = G[2] + ((c == 2) ? 1.f : 0.f);
        }

        accn += phys_norm(F, H);

        const float dx = cc[2].v[0] - T.v[0];
        const float dy = cc[2].v[1] - T.v[1];
        const float dz = cc[2].v[2] - T.v[2];
        accs += dx * dx + dy * dy + dz * dz;

        // ---- commit prefetched data into windows for next step ----
        if (i < XSEG - 1) {
            cc[0] = cc[1]; cc[1] = cc[2]; cc[2] = cc[3]; cc[3] = cc[4];
            cyp[0] = cyp[1]; cyp[1] = cyp[2];
            cym[0] = cym[1]; cym[1] = cym[2];
            const int nx0 = x0 + 1;
            if (nx0 + 2 <= 63)      cc[4] = cin;
            else if (nx0 + 2 == 64) cc[4] = comb2(2.f, cc[3], -1.f, cc[2]);
            else                    cc[4] = comb3(4.f, cc[2], -4.f, cc[1], 1.f, cc[0]);
            if (nx0 + 1 <= 63) {
                fixy1(ypin, ymin, cc[3], cyp[2], cym[2]);
            } else {
                cyp[2] = comb2(2.f, cyp[1], -1.f, cyp[0]);
                cym[2] = comb2(2.f, cym[1], -1.f, cym[0]);
            }
            fixy2(yp2in, ym2in, cc[2], cyp[1], cym[1], yp2, ym2);
        }
    }
#undef LDP

    const float invN = 1.0f / (float)NPTS;
    float val = 0.5f * accs * (invN * (1.0f / 3.0f)) + 0.5f * accn * invN;

    // ---- reduction: wave shuffle, then LDS across 8 waves ----
#pragma unroll
    for (int off = 32; off > 0; off >>= 1) val += __shfl_down(val, off, 64);

    __shared__ float wsum[8];
    if (lane == 0) wsum[wid] = val;
    __syncthreads();
    if (t == 0) {
        float acc = 0.0f;
#pragma unroll
        for (int wq = 0; wq < 8; wq++) acc += wsum[wq];
        atomicAdd(out, acc);
    }
}

extern "C" void kernel_launch(void* const* d_in, const int* in_sizes, int n_in,
                              void* d_out, int out_size, void* d_ws, size_t ws_size,
                              hipStream_t stream) {
    const float* pred = (const float*)d_in[0];
    const float* targ = (const float*)d_in[1];
    float* out = (float*)d_out;

    hipMemsetAsync(out, 0, sizeof(float), stream);

    const int blocks = 256;   // 2048 waves, one (b,y,xseg) strip each
    phys_loss_kernel<<<blocks, 512, 0, stream>>>(pred, targ, out);
}

// Round 18
// 29.322 us; speedup vs baseline: 1.3050x; 1.3050x over previous
//
#include <hip/hip_runtime.h>
#include <math.h>

#define ND 64
#define NPTS (4 * ND * ND * ND)   // 1,048,576
#define SXG (ND * ND * 3)         // 12288
#define SYG (ND * 3)              // 192
#define XSEG 8                    // x-steps marched per wave

struct f3 { float v[3]; };

__device__ __forceinline__ f3 comb2(float a, const f3& X, float s, const f3& Y) {
    f3 r;
#pragma unroll
    for (int c = 0; c < 3; c++) r.v[c] = a * X.v[c] + s * Y.v[c];
    return r;
}
__device__ __forceinline__ f3 comb3(float a, const f3& X, float s, const f3& Y, float u, const f3& Z) {
    f3 r;
#pragma unroll
    for (int c = 0; c < 3; c++) r.v[c] = a * X.v[c] + s * Y.v[c] + u * Z.v[c];
    return r;
}

// physics residual norm; H symmetric [c][6]: 0=xx 1=yy 2=zz 3=xy 4=xz 5=yz
// (verified r3-r13, absmax 0.0). NOTE: keep the reference-form tail — the
// factored variant (r17) adds live registers and tips the kernel into
// scratch spill (128-VGPR wall at 512-thread blocks).
__device__ __forceinline__ float phys_norm(const float F[3][3], const float H[3][6]) {
    constexpr int SYM[3][3] = {{0, 3, 4}, {3, 1, 5}, {4, 5, 2}};

    float cof[3][3];
#pragma unroll
    for (int i = 0; i < 3; i++) {
        const int i1 = (i + 1) % 3, i2 = (i + 2) % 3;
#pragma unroll
        for (int j = 0; j < 3; j++) {
            const int j1 = (j + 1) % 3, j2 = (j + 2) % 3;
            cof[i][j] = F[i1][j1] * F[i2][j2] - F[i1][j2] * F[i2][j1];
        }
    }

    float gc0[3][3], trg[3];
#pragma unroll
    for (int m = 0; m < 3; m++) {
        const int m1 = (m + 1) % 3, m2 = (m + 2) % 3;
        trg[m] = 0.0f;
#pragma unroll
        for (int i = 0; i < 3; i++) {
            const int i1 = (i + 1) % 3, i2 = (i + 2) % 3;
#pragma unroll
            for (int j = 0; j < 3; j++) {
                if (i == 0 || i == j) {
                    const float g = F[m2][i2] * H[m1][SYM[i1][j]] + F[m1][i1] * H[m2][SYM[i2][j]]
                                  - F[m2][i1] * H[m1][SYM[i2][j]] - F[m1][i2] * H[m2][SYM[i1][j]];
                    if (i == 0) gc0[m][j] = g;
                    if (i == j) trg[m] += g;
                }
            }
        }
    }

    const float J = F[0][0] * cof[0][0] + F[1][0] * cof[1][0] + F[2][0] * cof[2][0] + 1e-8f;
    const float invJ = 1.0f / J;

    float gJ[3];
#pragma unroll
    for (int j = 0; j < 3; j++) {
        gJ[j] = cof[0][0] * H[0][SYM[0][j]] + cof[1][0] * H[1][SYM[0][j]] + cof[2][0] * H[2][SYM[0][j]]
              + gc0[0][j] * F[0][0] + gc0[1][j] * F[1][0] + gc0[2][j] * F[2][0];
    }

    const float MU = 1000.0f, LMBD = 5000.0f;
    const float halfL = 0.5f * LMBD * (J * J - 1.0f);
    float r[3];
#pragma unroll
    for (int m = 0; m < 3; m++) {
        const float s1 = gJ[0] * cof[m][0] + gJ[1] * cof[m][1] + gJ[2] * cof[m][2];
        const float divInv = -invJ * invJ * s1 + invJ * trg[m];
        const float divF = H[m][0] + H[m][1] + H[m][2];
        float v = MU * (divF - divInv) + halfL * divInv + LMBD * s1;
        r[m] = (v != v) ? 0.0f : v;   // NaN -> 0
    }
    return sqrtf(r[0] * r[0] + r[1] * r[1] + r[2] * r[2]);
}

// Per-lane z-stencil coefficients (lane == z), verified r14 (absmax 0.0):
//   G2  = a1*d1r + a2*u1r + a3*vC
//   Hzz = b1*d1r + b2*u1r + b3*d2r + b4*u2r + b5*vC
//   Hcz = e1*Ds  + e2*Us  + e3*S     (S = difference field, D/U = shfl z+-1)
// Edge lanes read wrapped-garbage shuffles only through 0.0 coefficients.
struct ZC { float a1, a2, a3, b1, b2, b3, b4, b5, e1, e2, e3; };

__device__ __forceinline__ void comp_row(
        float vC, float Sx, float Sy, float sx2, float sy2, float dga,
        int ip1, int im1, int ip2, int im2, const ZC& q,
        float G[3], float Hr[6]) {
    const float d1r = __shfl(vC, ip1, 64), u1r = __shfl(vC, im1, 64);
    const float d2r = __shfl(vC, ip2, 64), u2r = __shfl(vC, im2, 64);
    const float Dx = __shfl(Sx, ip1, 64), Ux = __shfl(Sx, im1, 64);
    const float Dy = __shfl(Sy, ip1, 64), Uy = __shfl(Sy, im1, 64);

    G[0] = 0.5f * Sx;
    G[1] = 0.5f * Sy;
    G[2] = q.a1 * d1r + q.a2 * u1r + q.a3 * vC;
    Hr[0] = 0.25f * sx2 - 0.5f * vC;
    Hr[1] = 0.25f * sy2 - 0.5f * vC;
    Hr[2] = q.b1 * d1r + q.b2 * u1r + q.b3 * d2r + q.b4 * u2r + q.b5 * vC;
    Hr[3] = 0.25f * dga;
    Hr[4] = q.e1 * Dx + q.e2 * Ux + q.e3 * Sx;
    Hr[5] = q.e1 * Dy + q.e2 * Uy + q.e3 * Sy;
}

__global__ __launch_bounds__(512) void phys_loss_kernel(
        const float* __restrict__ pred,
        const float* __restrict__ targ,
        float* __restrict__ out) {
    const int t = threadIdx.x;
    const int lane = t & 63;
    const int wid = t >> 6;
    const int w = blockIdx.x * 8 + wid;     // 2048 waves
    const int y = w & 63;
    const int xseg = (w >> 6) & 7;
    const int b = w >> 9;
    const int z = lane;
    const int X0 = xseg * XSEG;

    const float* __restrict__ pb = pred + (size_t)b * (ND * SXG);
    const float* __restrict__ tb = targ + (size_t)b * (ND * SXG);
    const int yc1p = min(y + 1, 63), yc1m = max(y - 1, 0);
    const int yc2p = min(y + 2, 63), yc2m = max(y - 2, 0);

#define LDP(gx, gy) (*(const f3*)(pb + (size_t)((gx) * SXG + (gy) * SYG + z * 3)))

    auto fixy1 = [&](const f3& ypl, const f3& yml, const f3& cg, f3& ypc, f3& ymc) {
        if (y == 0)       { ypc = ypl; ymc = comb2(2.f, cg, -1.f, ypl); }
        else if (y == 63) { ymc = yml; ypc = comb2(2.f, cg, -1.f, yml); }
        else              { ypc = ypl; ymc = yml; }
    };
    auto fixy2 = [&](const f3& yp2l, const f3& ym2l, const f3& c0,
                     const f3& yp1, const f3& ym1, f3& o_p, f3& o_m) {
        if (y == 0)       { o_p = yp2l; o_m = comb3(4.f, c0, -4.f, yp1, 1.f, yp2l); }
        else if (y == 1)  { o_p = yp2l; o_m = comb2(2.f, ym1, -1.f, c0); }
        else if (y == 62) { o_m = ym2l; o_p = comb2(2.f, yp1, -1.f, c0); }
        else if (y == 63) { o_m = ym2l; o_p = comb3(4.f, c0, -4.f, ym1, 1.f, ym2l); }
        else              { o_p = yp2l; o_m = ym2l; }
    };

    // ---- prologue: windows for x0 = X0 ----
    f3 cc[5], cyp[3], cym[3], yp2, ym2;
    if (X0 == 0) {
        cc[2] = LDP(0, y); cc[3] = LDP(1, y); cc[4] = LDP(2, y);
        cc[1] = comb2(2.f, cc[2], -1.f, cc[3]);
        cc[0] = comb3(4.f, cc[2], -4.f, cc[3], 1.f, cc[4]);
        { f3 a = LDP(0, yc1p), bq = LDP(0, yc1m); fixy1(a, bq, cc[2], cyp[1], cym[1]); }
        { f3 a = LDP(1, yc1p), bq = LDP(1, yc1m); fixy1(a, bq, cc[3], cyp[2], cym[2]); }
        cyp[0] = comb2(2.f, cyp[1], -1.f, cyp[2]);
        cym[0] = comb2(2.f, cym[1], -1.f, cym[2]);
    } else {
#pragma unroll
        for (int k = 0; k < 5; k++) cc[k] = LDP(X0 - 2 + k, y);
#pragma unroll
        for (int k = 0; k < 3; k++) {
            f3 a = LDP(X0 - 1 + k, yc1p), bq = LDP(X0 - 1 + k, yc1m);
            fixy1(a, bq, cc[k + 1], cyp[k], cym[k]);
        }
    }
    { f3 a = LDP(X0, yc2p), bq = LDP(X0, yc2m);
      fixy2(a, bq, cc[2], cyp[1], cym[1], yp2, ym2); }

    // ---- per-lane z-stencil coefficients (once per wave) ----
    ZC q = {0.5f, -0.5f, 0.f,  0.f, 0.f, 0.25f, 0.25f, -0.5f,  0.25f, -0.25f, 0.f};
    if (z == 0)  { q = {1.f, 0.f, -1.f,  -1.f, 0.f, 0.5f, 0.f, 0.5f,   0.5f, 0.f, -0.5f}; }
    if (z == 1)  { q.b1 = 0.f; q.b2 = 0.5f; q.b3 = 0.25f; q.b4 = 0.f; q.b5 = -0.75f; }
    if (z == 62) { q.b1 = 0.5f; q.b2 = 0.f; q.b3 = 0.f; q.b4 = 0.25f; q.b5 = -0.75f; }
    if (z == 63) { q = {0.f, -1.f, 1.f,  0.f, -1.f, 0.f, 0.5f, 0.5f,  0.f, -0.5f, 0.5f}; }

    const int ip1 = (lane + 1) & 63, im1 = (lane + 63) & 63;
    const int ip2 = (lane + 2) & 63, im2 = (lane + 62) & 63;

    float accn = 0.f, accs = 0.f;

#pragma unroll 2
    for (int i = 0; i < XSEG; i++) {
        const int x0 = X0 + i;

        // ---- prefetch raw (clamped) columns for next step ----
        f3 cin, ypin, ymin, yp2in, ym2in;
        if (i < XSEG - 1) {
            const int gxc = min(x0 + 3, 63);
            const int gx1 = min(x0 + 2, 63);
            cin  = LDP(gxc, y);
            ypin = LDP(gx1, yc1p);  ymin = LDP(gx1, yc1m);
            yp2in = LDP(x0 + 1, yc2p);  ym2in = LDP(x0 + 1, yc2m);
        }
        const f3 T = *(const f3*)(tb + (size_t)(x0 * SXG + y * SYG + z * 3));

        // ---- compute current step from windows ----
        float F[3][3], H[3][6], G[3];
#pragma unroll
        for (int c = 0; c < 3; c++) {
            const float Sx  = cc[3].v[c] - cc[1].v[c];
            const float Sy  = cyp[1].v[c] - cym[1].v[c];
            const float sx2 = cc[4].v[c] + cc[0].v[c];
            const float sy2 = yp2.v[c] + ym2.v[c];
            const float dga = (cyp[2].v[c] - cyp[0].v[c]) - (cym[2].v[c] - cym[0].v[c]);
            comp_row(cc[2].v[c], Sx, Sy, sx2, sy2, dga,
                     ip1, im1, ip2, im2, q, G, H[c]);
            F[c][0] = G[0] + ((c == 0) ? 1.f : 0.f);
            F[c][1] = G[1] + ((c == 1) ? 1.f : 0.f);
            F[c][2] = G[2] + ((c == 2) ? 1.f : 0.f);
        }

        accn += phys_norm(F, H);

        const float dx = cc[2].v[0] - T.v[0];
        const float dy = cc[2].v[1] - T.v[1];
        const float dz = cc[2].v[2] - T.v[2];
        accs += dx * dx + dy * dy + dz * dz;

        // ---- commit prefetched data into windows for next step ----
        if (i < XSEG - 1) {
            cc[0] = cc[1]; cc[1] = cc[2]; cc[2] = cc[3]; cc[3] = cc[4];
            cyp[0] = cyp[1]; cyp[1] = cyp[2];
            cym[0] = cym[1]; cym[1] = cym[2];
            const int nx0 = x0 + 1;
            if (nx0 + 2 <= 63)      cc[4] = cin;
            else if (nx0 + 2 == 64) cc[4] = comb2(2.f, cc[3], -1.f, cc[2]);
            else                    cc[4] = comb3(4.f, cc[2], -4.f, cc[1], 1.f, cc[0]);
            if (nx0 + 1 <= 63) {
                fixy1(ypin, ymin, cc[3], cyp[2], cym[2]);
            } else {
                cyp[2] = comb2(2.f, cyp[1], -1.f, cyp[0]);
                cym[2] = comb2(2.f, cym[1], -1.f, cym[0]);
            }
            fixy2(yp2in, ym2in, cc[2], cyp[1], cym[1], yp2, ym2);
        }
    }
#undef LDP

    const float invN = 1.0f / (float)NPTS;
    float val = 0.5f * accs * (invN * (1.0f / 3.0f)) + 0.5f * accn * invN;

    // ---- reduction: wave shuffle, then LDS across 8 waves ----
#pragma unroll
    for (int off = 32; off > 0; off >>= 1) val += __shfl_down(val, off, 64);

    __shared__ float wsum[8];
    if (lane == 0) wsum[wid] = val;
    __syncthreads();
    if (t == 0) {
        float acc = 0.0f;
#pragma unroll
        for (int wq = 0; wq < 8; wq++) acc += wsum[wq];
        atomicAdd(out, acc);
    }
}

extern "C" void kernel_launch(void* const* d_in, const int* in_sizes, int n_in,
                              void* d_out, int out_size, void* d_ws, size_t ws_size,
                              hipStream_t stream) {
    const float* pred = (const float*)d_in[0];
    const float* targ = (const float*)d_in[1];
    float* out = (float*)d_out;

    hipMemsetAsync(out, 0, sizeof(float), stream);

    const int blocks = 256;   // 2048 waves, one (b,y,xseg) strip each
    phys_loss_kernel<<<blocks, 512, 0, stream>>>(pred, targ, out);
}